// Round 12
// baseline (1632.126 us; speedup 1.0000x reference)
//
#include <hip/hip_runtime.h>
#include <math.h>

#define B_ 4
#define T_ 10
#define H_ 144
#define W_ 256
#define F_ 64

typedef __attribute__((ext_vector_type(8))) __bf16 bf16x8;
typedef __attribute__((ext_vector_type(4))) float f32x4;

static __device__ __forceinline__ float hs_(float x) {
    return fminf(fmaxf(fmaf(x, 0.2f, 0.5f), 0.f), 1.f);
}
static __device__ __forceinline__ unsigned short f2bf(float f) {
    unsigned u = __builtin_bit_cast(unsigned, f);
    u += 0x7fff + ((u >> 16) & 1);
    return (unsigned short)(u >> 16);
}
static __device__ __forceinline__ float bf2f(unsigned short s) {
    unsigned u = ((unsigned)s) << 16;
    return __builtin_bit_cast(float, u);
}
static __device__ __forceinline__ void gl_lds16(const void* gp, void* lp) {
    __builtin_amdgcn_global_load_lds(
        (const __attribute__((address_space(1))) unsigned int*)gp,
        (__attribute__((address_space(3))) unsigned int*)lp, 16, 0, 0);
}
static __device__ __forceinline__ unsigned lds_addr(void* p) {
    return (unsigned)(unsigned long long)(__attribute__((address_space(3))) char*)p;
}

// ---- repack Wh [5][5][64][256] -> [25][2][4 gate][4 wf][64 lane][8] bf16 ----
__global__ void repack_wh_mfma(const float* __restrict__ w, unsigned short* __restrict__ o) {
    int idx = blockIdx.x * 256 + threadIdx.x;
    if (idx >= 25 * 2 * 4 * 4 * 64) return;
    int l = idx & 63;
    int wf = (idx >> 6) & 3;
    int g = (idx >> 8) & 3;
    int ch = (idx >> 10) & 1;
    int tap = idx >> 11;
    int n = g * 64 + wf * 16 + (l & 15);
    unsigned short* dst = o + (size_t)idx * 8;
#pragma unroll
    for (int j = 0; j < 8; ++j) {
        int c = ch * 32 + (l >> 4) * 8 + j;
        dst[j] = f2bf(w[((size_t)(tap * 64 + c)) * 256 + n]);
    }
}

// ---- repack Wx [5][5][3][256] -> [5 ky][4 gate][4 wf][64 lane][8] bf16 ----
__global__ void repack_wx_mfma(const float* __restrict__ w, unsigned short* __restrict__ o) {
    int idx = blockIdx.x * 256 + threadIdx.x;
    if (idx >= 5 * 4 * 4 * 64) return;
    int l = idx & 63;
    int wf = (idx >> 6) & 3;
    int g = (idx >> 8) & 3;
    int ky = idx >> 10;
    int n = g * 64 + wf * 16 + (l & 15);
    unsigned short* dst = o + (size_t)idx * 8;
#pragma unroll
    for (int j = 0; j < 8; ++j) {
        int k = (l >> 4) * 8 + j;
        unsigned short v = 0;
        if (k < 15) {
            int kx = k / 3, c = k - kx * 3;
            v = f2bf(w[((size_t)((ky * 5 + kx) * 3 + c)) * 256 + n]);
        }
        dst[j] = v;
    }
}

// ---- generic conv weight repack: [taps][CIN][COUT] f32 -> [tap][2ch][NF][64][8] bf16 ----
__global__ void repack_conv(const float* __restrict__ w, unsigned short* __restrict__ o,
                            int taps, int cin, int cout) {
    int NF = cout >> 4;
    int total = taps * 2 * NF * 64;
    int idx = blockIdx.x * 256 + threadIdx.x;
    if (idx >= total) return;
    int l = idx & 63;
    int nf = (idx >> 6) % NF;
    int ch = ((idx >> 6) / NF) & 1;
    int tap = (idx >> 6) / NF / 2;
    int n = nf * 16 + (l & 15);
    unsigned short* dst = o + (size_t)idx * 8;
#pragma unroll
    for (int j = 0; j < 8; ++j) {
        int c = ch * 32 + (l >> 4) * 8 + j;
        dst[j] = (c < cin) ? f2bf(w[((size_t)(tap * cin + c)) * cout + n]) : (unsigned short)0;
    }
}

// ---- fused ConvLSTM step; wave-private LDS B-staging, counted vmcnt, NO barrier in K-loop ----
// block = 4 waves; wave w: 64 px x f [16w,16w+16) x all 4 gates
// LDS h-tile row ky: byte = ((ky*68+px)*128 + cg*16) ^ ((px&7)<<4)
// B slice per wave per step: 4KB at sB[s&1] + w*1024 (+g*4096), lane l reads/writes +l*16
#define MT 64
__global__ __launch_bounds__(256, 2) void lstm_mfma(
    const float* __restrict__ x,
    const unsigned short* __restrict__ wxr,
    const unsigned short* __restrict__ whr,
    const float* __restrict__ bias,
    const unsigned short* __restrict__ h_prev,
    unsigned short* __restrict__ h_out,
    float* __restrict__ c_io,
    int t, int first)
{
    __shared__ char sh[5 * 68 * 128];           // swizzled bf16 h tile = 43520 B
    __shared__ unsigned short sxr[5 * 72 * 4];  // raw bf16 x tile = 2880 B
    __shared__ __align__(16) char sB[2][16384]; // B double buffer = 32768 B

    const int b = blockIdx.z, y = blockIdx.y, x0 = blockIdx.x * MT;
    const int tid = threadIdx.x;
    const int w = tid >> 6, l = tid & 63;
    const int m0 = l & 15, kq = l >> 4;

    // per-thread k -> (kx*4+c) table for x A-frag gathers (invalid -> c=3 zero slot)
    int dj[8];
#pragma unroll
    for (int j = 0; j < 8; ++j) {
        int k = kq * 8 + j;
        int kx = k / 3, c = k - kx * 3;
        dj[j] = (k < 15) ? kx * 4 + c : 3;
    }

    // zero the c=3 column (read by pad lanes)
    for (int e = tid; e < 5 * 68; e += 256) {
        int ky = e / 68, px = e - ky * 68;
        sxr[(ky * 72 + px) * 4 + 3] = 0;
    }
    // stage raw x tile
    for (int e = tid; e < 5 * 68 * 3; e += 256) {
        int ky = e / 204;
        int rem = e - ky * 204;
        int px = rem / 3, c = rem - px * 3;
        int yg = y + ky - 2, xg = x0 + px - 2;
        float v = 0.f;
        if (yg >= 0 && yg < H_ && (unsigned)xg < W_)
            v = x[(((size_t)((b * T_ + t) * H_ + yg)) * W_ + xg) * 3 + c];
        sxr[(ky * 72 + px) * 4 + c] = f2bf(v);
    }
    // stage h tile (bf16, XOR-swizzled rows) + issue DMA for h-step 0
    if (!first) {
        for (int e = tid; e < 5 * 68 * 8; e += 256) {
            int ky = e / (68 * 8);
            int rem = e - ky * 68 * 8;
            int px = rem >> 3, cg = rem & 7;
            int yg = y + ky - 2, xg = x0 + px - 2;
            uint4 v = make_uint4(0, 0, 0, 0);
            if (yg >= 0 && yg < H_ && (unsigned)xg < W_)
                v = *(const uint4*)(h_prev + ((((size_t)(b * H_ + yg)) * W_ + xg) << 6) + cg * 8);
            int off = ((ky * 68 + px) * 128 + cg * 16) ^ ((px & 7) << 4);
            *(uint4*)(sh + off) = v;
        }
        {
            const char* g0 = (const char*)whr + (size_t)tid * 16;
            char* d0 = &sB[0][(size_t)w << 10];
#pragma unroll
            for (int q = 0; q < 4; ++q)
                gl_lds16(g0 + q * 4096, d0 + q * 4096);
        }
    }
    __syncthreads();  // drains staging stores and DMA(0)

    f32x4 acc[4][4];
#pragma unroll
    for (int rf = 0; rf < 4; ++rf)
#pragma unroll
        for (int g = 0; g < 4; ++g) acc[rf][g] = (f32x4){0.f, 0.f, 0.f, 0.f};

    // x-conv: 5 K-steps, A built from raw tile via scalar LDS gathers
    for (int ky = 0; ky < 5; ++ky) {
        bf16x8 a[4], bb[4];
#pragma unroll
        for (int rf = 0; rf < 4; ++rf) {
            int base = (ky * 72 + rf * 16 + m0) * 4;
            union { bf16x8 v; unsigned short u[8]; } tt;
#pragma unroll
            for (int j = 0; j < 8; ++j) tt.u[j] = sxr[base + dj[j]];
            a[rf] = tt.v;
        }
#pragma unroll
        for (int g = 0; g < 4; ++g)
            bb[g] = *(const bf16x8*)(wxr + ((size_t)((ky * 16 + g * 4 + w) * 64 + l)) * 8);
#pragma unroll
        for (int rf = 0; rf < 4; ++rf)
#pragma unroll
            for (int g = 0; g < 4; ++g)
                acc[rf][g] = __builtin_amdgcn_mfma_f32_16x16x32_bf16(a[rf], bb[g], acc[rf][g], 0, 0, 0);
    }

    // h-conv: 50 K-steps, fully unrolled; per step: issue DMA(s+1) | vmcnt(4) | asm B-reads
    // from own slice | A-reads | lgkmcnt(0)+sched_barrier | 16 MFMA.  No barriers.
    if (!first) {
        int V[5][2];
#pragma unroll
        for (int kx = 0; kx < 5; ++kx) {
            int T = ((m0 + kx) & 7) << 4;
#pragma unroll
            for (int ch = 0; ch < 2; ++ch)
                V[kx][ch] = ((m0 + kx) * 128 + ch * 64 + kq * 16) ^ T;
        }
        const char* shb = sh;
        const unsigned bq0 = lds_addr(&sB[0][0]) + (unsigned)(w * 1024 + l * 16);
        const unsigned bq1 = bq0 + 16384;

#define DMA_(S)                                                                 \
        { const char* gs_ = (const char*)whr + (size_t)(S) * 16384 + (size_t)tid * 16; \
          char* ds_ = &sB[(S) & 1][(size_t)w << 10];                            \
          _Pragma("unroll")                                                     \
          for (int q = 0; q < 4; ++q) gl_lds16(gs_ + q * 4096, ds_ + q * 4096); }

#define HSTEP_(S)                                                               \
        {                                                                       \
            if ((S) + 1 < 50) { DMA_((S) + 1); }                                \
            __builtin_amdgcn_sched_barrier(0);                                  \
            if ((S) + 1 < 50) { asm volatile("s_waitcnt vmcnt(4)" ::: "memory"); } \
            else              { asm volatile("s_waitcnt vmcnt(0)" ::: "memory"); } \
            const unsigned bq_ = ((S) & 1) ? bq1 : bq0;                         \
            bf16x8 b0_, b1_, b2_, b3_;                                          \
            asm volatile("ds_read_b128 %0, %4\n\t"                              \
                         "ds_read_b128 %1, %4 offset:4096\n\t"                  \
                         "ds_read_b128 %2, %4 offset:8192\n\t"                  \
                         "ds_read_b128 %3, %4 offset:12288"                     \
                         : "=v"(b0_), "=v"(b1_), "=v"(b2_), "=v"(b3_)           \
                         : "v"(bq_));                                           \
            bf16x8 a_[4];                                                       \
            _Pragma("unroll")                                                   \
            for (int rf = 0; rf < 4; ++rf)                                      \
                a_[rf] = *(const bf16x8*)(shb + (V[((S) % 10) >> 1][(S) & 1]    \
                                        + (((S) / 10) * 8704 + rf * 2048)));    \
            asm volatile("s_waitcnt lgkmcnt(0)" ::: "memory");                  \
            __builtin_amdgcn_sched_barrier(0);                                  \
            _Pragma("unroll")                                                   \
            for (int rf = 0; rf < 4; ++rf) {                                    \
                acc[rf][0] = __builtin_amdgcn_mfma_f32_16x16x32_bf16(a_[rf], b0_, acc[rf][0], 0, 0, 0); \
                acc[rf][1] = __builtin_amdgcn_mfma_f32_16x16x32_bf16(a_[rf], b1_, acc[rf][1], 0, 0, 0); \
                acc[rf][2] = __builtin_amdgcn_mfma_f32_16x16x32_bf16(a_[rf], b2_, acc[rf][2], 0, 0, 0); \
                acc[rf][3] = __builtin_amdgcn_mfma_f32_16x16x32_bf16(a_[rf], b3_, acc[rf][3], 0, 0, 0); \
            }                                                                   \
        }

#define H2_(S)  HSTEP_(S) HSTEP_((S) + 1)
#define H10_(S) H2_(S) H2_((S) + 2) H2_((S) + 4) H2_((S) + 6) H2_((S) + 8)
        H10_(0) H10_(10) H10_(20) H10_(30) H10_(40)
#undef DMA_
#undef HSTEP_
#undef H2_
#undef H10_
    }

    const int f = (w << 4) + m0;
    const float bi0 = bias[f], bi1 = bias[64 + f], bi2 = bias[128 + f], bi3 = bias[192 + f];
#pragma unroll
    for (int rf = 0; rf < 4; ++rf) {
#pragma unroll
        for (int r = 0; r < 4; ++r) {
            int px = x0 + rf * 16 + kq * 4 + r;
            size_t idx = ((((size_t)(b * H_ + y)) * W_ + px) << 6) + f;
            float zi = acc[rf][0][r] + bi0;
            float zf = acc[rf][1][r] + bi1;
            float zc = acc[rf][2][r] + bi2;
            float zo = acc[rf][3][r] + bi3;
            float cp = first ? 0.f : c_io[idx];
            float cn = hs_(zf) * cp + hs_(zi) * tanhf(zc);
            float hn = hs_(zo) * tanhf(cn);
            c_io[idx] = cn;
            h_out[idx] = f2bf(hn);
        }
    }
}

// -------- BatchNorm (inference), bf16 in -> bf16 out --------
__global__ void bn_k(const unsigned short* __restrict__ in, unsigned short* __restrict__ out,
                     const float* __restrict__ gamma, const float* __restrict__ beta,
                     const float* __restrict__ mean, const float* __restrict__ var, int n) {
    for (int i = blockIdx.x * blockDim.x + threadIdx.x; i < n; i += gridDim.x * blockDim.x) {
        int c = i & 63;
        float s = rsqrtf(var[c] + 1e-3f) * gamma[c];
        out[i] = f2bf((bf2f(in[i]) - mean[c]) * s + beta[c]);
    }
}

// ---- generic MFMA conv: bf16 in [B,H,W,CIN] -> ReLU -> bf16 out [B,H,W,COUT] ----
template <int KH, int KW, int CIN, int COUT, int KYB>
__global__ __launch_bounds__(256) void conv_mfma(
    const unsigned short* __restrict__ in, const unsigned short* __restrict__ wr,
    const float* __restrict__ bias, unsigned short* __restrict__ out)
{
    constexpr int TC = 64 + KW - 1;
    constexpr int PADX = KW / 2, PADY = KH / 2;
    constexpr int NF = COUT / 16;
    constexpr int CHN = (CIN + 31) / 32;
    constexpr int NKG = KH / KYB;
    __shared__ char sh[KYB * TC * 128];

    const int b = blockIdx.z, y = blockIdx.y, x0 = blockIdx.x * 64;
    const int tid = threadIdx.x;
    const int w = tid >> 6, l = tid & 63;
    const int m0 = l & 15, kq = l >> 4;

    f32x4 acc[NF];
#pragma unroll
    for (int nf = 0; nf < NF; ++nf) acc[nf] = (f32x4){0.f, 0.f, 0.f, 0.f};

    for (int kg = 0; kg < NKG; ++kg) {
        __syncthreads();
        for (int e = tid; e < KYB * TC * 8; e += 256) {
            int kyl = e / (TC * 8);
            int rem = e - kyl * TC * 8;
            int px = rem >> 3, cg = rem & 7;
            int ky = kg * KYB + kyl;
            int yg = y + ky - PADY, xg = x0 + px - PADX;
            int c0 = cg * 8;
            uint4 v = make_uint4(0, 0, 0, 0);
            if (yg >= 0 && yg < H_ && (unsigned)xg < W_ && c0 < CIN)
                v = *(const uint4*)(in + ((size_t)((b * H_ + yg) * W_) + xg) * CIN + c0);
            int off = ((kyl * TC + px) * 128 + cg * 16) ^ ((px & 7) << 4);
            *(uint4*)(sh + off) = v;
        }
        __syncthreads();

        for (int kyl = 0; kyl < KYB; ++kyl) {
            int ky = kg * KYB + kyl;
#pragma unroll
            for (int kx = 0; kx < KW; ++kx) {
#pragma unroll
                for (int ch = 0; ch < CHN; ++ch) {
                    int px = w * 16 + m0 + kx;
                    int off = ((kyl * TC + px) * 128 + ch * 64 + kq * 16) ^ ((px & 7) << 4);
                    bf16x8 a = *(const bf16x8*)(sh + off);
                    int tap = ky * KW + kx;
                    const unsigned short* wp = wr + ((size_t)(((tap * 2 + ch) * NF) * 64 + l)) * 8;
#pragma unroll
                    for (int nf = 0; nf < NF; ++nf) {
                        bf16x8 bb = *(const bf16x8*)(wp + nf * 512);
                        acc[nf] = __builtin_amdgcn_mfma_f32_16x16x32_bf16(a, bb, acc[nf], 0, 0, 0);
                    }
                }
            }
        }
    }

#pragma unroll
    for (int nf = 0; nf < NF; ++nf) {
        int cout = nf * 16 + m0;
        float bv = bias[cout];
#pragma unroll
        for (int r = 0; r < 4; ++r) {
            int px = x0 + w * 16 + kq * 4 + r;
            float v = fmaxf(acc[nf][r] + bv, 0.f);
            out[((size_t)((b * H_ + y) * W_) + px) * COUT + cout] = f2bf(v);
        }
    }
}

// -------- conv5: 3x3, 64 -> 3, sigmoid; bf16 in, f32 out --------
__global__ __launch_bounds__(256) void conv5_k(
    const unsigned short* __restrict__ in, const float* __restrict__ wgt,
    const float* __restrict__ bias, float* __restrict__ out)
{
    constexpr int CC = 16;
    __shared__ float s[3][W_ + 2][CC + 1];
    const int b = blockIdx.z, y = blockIdx.y;
    const int tid = threadIdx.x;

    float acc[3] = {0.f, 0.f, 0.f};
    for (int c0 = 0; c0 < 64; c0 += CC) {
        __syncthreads();
        for (int e = tid; e < 3 * (W_ + 2) * CC; e += 256) {
            int r = e / ((W_ + 2) * CC);
            int rem = e % ((W_ + 2) * CC);
            int cc = rem / CC, ch = rem % CC;
            int yg = y + r - 1, xg = cc - 1;
            float v = 0.f;
            if (yg >= 0 && yg < H_ && xg >= 0 && xg < W_)
                v = bf2f(in[((b * H_ + yg) * W_ + xg) * 64 + c0 + ch]);
            s[r][cc][ch] = v;
        }
        __syncthreads();
        for (int ky = 0; ky < 3; ++ky) {
#pragma unroll
            for (int kx = 0; kx < 3; ++kx) {
                for (int c = 0; c < CC; ++c) {
                    const float* wp = &wgt[((ky * 3 + kx) * 64 + c0 + c) * 3];
                    float v = s[ky][tid + kx][c];
                    acc[0] = fmaf(v, wp[0], acc[0]);
                    acc[1] = fmaf(v, wp[1], acc[1]);
                    acc[2] = fmaf(v, wp[2], acc[2]);
                }
            }
        }
    }
#pragma unroll
    for (int j = 0; j < 3; ++j) {
        float v = acc[j] + bias[j];
        v = 1.f / (1.f + expf(-v));
        out[((b * H_ + y) * W_ + tid) * 3 + j] = v;
    }
}

extern "C" void kernel_launch(void* const* d_in, const int* in_sizes, int n_in,
                              void* d_out, int out_size, void* d_ws, size_t ws_size,
                              hipStream_t stream) {
    const float* x     = (const float*)d_in[0];
    const float* Wx    = (const float*)d_in[1];
    const float* Wh    = (const float*)d_in[2];
    const float* bl    = (const float*)d_in[3];
    const float* gamma = (const float*)d_in[4];
    const float* beta  = (const float*)d_in[5];
    const float* mmean = (const float*)d_in[6];
    const float* mvar  = (const float*)d_in[7];
    const float* W1 = (const float*)d_in[8];
    const float* b1 = (const float*)d_in[9];
    const float* W2 = (const float*)d_in[10];
    const float* b2 = (const float*)d_in[11];
    const float* W3 = (const float*)d_in[12];
    const float* b3 = (const float*)d_in[13];
    const float* W4 = (const float*)d_in[14];
    const float* b4 = (const float*)d_in[15];
    const float* W5 = (const float*)d_in[16];
    const float* b5 = (const float*)d_in[17];
    float* out = (float*)d_out;

    const size_t NHWF = (size_t)B_ * H_ * W_ * 64;  // 9.44M
    char* p = (char*)d_ws;
    float* c_buf = (float*)p;                 p += NHWF * 4;
    unsigned short* hA = (unsigned short*)p;  p += NHWF * 2;
    unsigned short* hB = (unsigned short*)p;  p += NHWF * 2;
    unsigned short* whr = (unsigned short*)p; p += (size_t)25 * 2 * 16 * 64 * 8 * 2;
    unsigned short* wxr = (unsigned short*)p; p += (size_t)5 * 16 * 64 * 8 * 2;
    unsigned short* w1r = (unsigned short*)p; p += (size_t)81 * 2 * 1 * 512 * 2;
    unsigned short* w2r = (unsigned short*)p; p += (size_t)25 * 2 * 2 * 512 * 2;
    unsigned short* w3r = (unsigned short*)p; p += (size_t)9 * 2 * 4 * 512 * 2;
    unsigned short* w4r = (unsigned short*)p; p += (size_t)9 * 2 * 4 * 512 * 2;

    repack_wh_mfma<<<(25 * 2 * 4 * 4 * 64 + 255) / 256, 256, 0, stream>>>(Wh, whr);
    repack_wx_mfma<<<(5 * 4 * 4 * 64 + 255) / 256, 256, 0, stream>>>(Wx, wxr);
    repack_conv<<<(81 * 2 * 1 * 64 + 255) / 256, 256, 0, stream>>>(W1, w1r, 81, 64, 16);
    repack_conv<<<(25 * 2 * 2 * 64 + 255) / 256, 256, 0, stream>>>(W2, w2r, 25, 16, 32);
    repack_conv<<<(9 * 2 * 4 * 64 + 255) / 256, 256, 0, stream>>>(W3, w3r, 9, 32, 64);
    repack_conv<<<(9 * 2 * 4 * 64 + 255) / 256, 256, 0, stream>>>(W4, w4r, 9, 64, 64);

    dim3 lgrid(W_ / MT, H_, B_);
    for (int t = 0; t < T_; ++t) {
        const unsigned short* hp = (t & 1) ? hA : hB;
        unsigned short* ho = (t & 1) ? hB : hA;
        lstm_mfma<<<lgrid, 256, 0, stream>>>(x, wxr, whr, bl, hp, ho, c_buf, t, t == 0 ? 1 : 0);
    }
    // final h in hB

    unsigned short* bnb = hA;
    bn_k<<<2048, 256, 0, stream>>>(hB, bnb, gamma, beta, mmean, mvar, (int)NHWF);

    unsigned short* o1 = (unsigned short*)c_buf;
    unsigned short* o2 = o1 + NHWF / 4;
    unsigned short* o3 = hB;
    unsigned short* o4 = hA;

    dim3 cgrid(W_ / 64, H_, B_);
    conv_mfma<9, 9, 64, 16, 3><<<cgrid, 256, 0, stream>>>(bnb, w1r, b1, o1);
    conv_mfma<5, 5, 16, 32, 5><<<cgrid, 256, 0, stream>>>(o1, w2r, b2, o2);
    conv_mfma<3, 3, 32, 64, 3><<<cgrid, 256, 0, stream>>>(o2, w3r, b3, o3);
    conv_mfma<3, 3, 64, 64, 3><<<cgrid, 256, 0, stream>>>(o3, w4r, b4, o4);
    conv5_k<<<dim3(1, H_, B_), 256, 0, stream>>>(o4, W5, b5, out);
}

// Round 13
// 1506.382 us; speedup vs baseline: 1.0835x; 1.0835x over previous
//
#include <hip/hip_runtime.h>
#include <math.h>

#define B_ 4
#define T_ 10
#define H_ 144
#define W_ 256
#define F_ 64

typedef __attribute__((ext_vector_type(8))) __bf16 bf16x8;
typedef __attribute__((ext_vector_type(4))) float f32x4;

static __device__ __forceinline__ float hs_(float x) {
    return fminf(fmaxf(fmaf(x, 0.2f, 0.5f), 0.f), 1.f);
}
static __device__ __forceinline__ unsigned short f2bf(float f) {
    unsigned u = __builtin_bit_cast(unsigned, f);
    u += 0x7fff + ((u >> 16) & 1);
    return (unsigned short)(u >> 16);
}
static __device__ __forceinline__ float bf2f(unsigned short s) {
    unsigned u = ((unsigned)s) << 16;
    return __builtin_bit_cast(float, u);
}

// ---- repack Wh [5][5][64][256] -> [25][2][4 gate][4 wf][64 lane][8] bf16 ----
__global__ void repack_wh_mfma(const float* __restrict__ w, unsigned short* __restrict__ o) {
    int idx = blockIdx.x * 256 + threadIdx.x;
    if (idx >= 25 * 2 * 4 * 4 * 64) return;
    int l = idx & 63;
    int wf = (idx >> 6) & 3;
    int g = (idx >> 8) & 3;
    int ch = (idx >> 10) & 1;
    int tap = idx >> 11;
    int n = g * 64 + wf * 16 + (l & 15);
    unsigned short* dst = o + (size_t)idx * 8;
#pragma unroll
    for (int j = 0; j < 8; ++j) {
        int c = ch * 32 + (l >> 4) * 8 + j;
        dst[j] = f2bf(w[((size_t)(tap * 64 + c)) * 256 + n]);
    }
}

// ---- repack Wx [5][5][3][256] -> [5 ky][4 gate][4 wf][64 lane][8] bf16 ----
__global__ void repack_wx_mfma(const float* __restrict__ w, unsigned short* __restrict__ o) {
    int idx = blockIdx.x * 256 + threadIdx.x;
    if (idx >= 5 * 4 * 4 * 64) return;
    int l = idx & 63;
    int wf = (idx >> 6) & 3;
    int g = (idx >> 8) & 3;
    int ky = idx >> 10;
    int n = g * 64 + wf * 16 + (l & 15);
    unsigned short* dst = o + (size_t)idx * 8;
#pragma unroll
    for (int j = 0; j < 8; ++j) {
        int k = (l >> 4) * 8 + j;
        unsigned short v = 0;
        if (k < 15) {
            int kx = k / 3, c = k - kx * 3;
            v = f2bf(w[((size_t)((ky * 5 + kx) * 3 + c)) * 256 + n]);
        }
        dst[j] = v;
    }
}

// ---- generic conv weight repack: [taps][CIN][COUT] f32 -> [tap][2ch][NF][64][8] bf16 ----
__global__ void repack_conv(const float* __restrict__ w, unsigned short* __restrict__ o,
                            int taps, int cin, int cout) {
    int NF = cout >> 4;
    int total = taps * 2 * NF * 64;
    int idx = blockIdx.x * 256 + threadIdx.x;
    if (idx >= total) return;
    int l = idx & 63;
    int nf = (idx >> 6) % NF;
    int ch = ((idx >> 6) / NF) & 1;
    int tap = (idx >> 6) / NF / 2;
    int n = nf * 16 + (l & 15);
    unsigned short* dst = o + (size_t)idx * 8;
#pragma unroll
    for (int j = 0; j < 8; ++j) {
        int c = ch * 32 + (l >> 4) * 8 + j;
        dst[j] = (c < cin) ? f2bf(w[((size_t)(tap * cin + c)) * cout + n]) : (unsigned short)0;
    }
}

// ---- fused ConvLSTM step via bf16 MFMA (r11 structure = best measured) ----
// block = 4 waves; wave w: 64 px x f [16w,16w+16) x all 4 gates
// LDS h-tile row ky: byte = ((ky*68+px)*128 + cg*16) ^ ((px&7)<<4)
// A addr = V[kx][ch] + ky*8704 + rf*2048
// last!=0: fuse BatchNorm into epilogue (write BN'd h, skip c write)
#define MT 64
__global__ __launch_bounds__(256, 3) void lstm_mfma(
    const float* __restrict__ x,
    const unsigned short* __restrict__ wxr,
    const unsigned short* __restrict__ whr,
    const float* __restrict__ bias,
    const unsigned short* __restrict__ h_prev,
    unsigned short* __restrict__ h_out,
    float* __restrict__ c_io,
    const float* __restrict__ gamma,
    const float* __restrict__ beta,
    const float* __restrict__ mmean,
    const float* __restrict__ mvar,
    int t, int first, int last)
{
    __shared__ char sh[5 * 68 * 128];           // swizzled bf16 h tile = 43520 B
    __shared__ unsigned short sxr[5 * 72 * 4];  // raw bf16 x tile = 2880 B

    const int b = blockIdx.z, y = blockIdx.y, x0 = blockIdx.x * MT;
    const int tid = threadIdx.x;
    const int w = tid >> 6, l = tid & 63;
    const int m0 = l & 15, kq = l >> 4;

    // per-thread k -> (kx*4+c) table for x A-frag gathers (invalid -> c=3 zero slot)
    int dj[8];
#pragma unroll
    for (int j = 0; j < 8; ++j) {
        int k = kq * 8 + j;
        int kx = k / 3, c = k - kx * 3;
        dj[j] = (k < 15) ? kx * 4 + c : 3;
    }

    // zero the c=3 column (read by pad lanes)
    for (int e = tid; e < 5 * 68; e += 256) {
        int ky = e / 68, px = e - ky * 68;
        sxr[(ky * 72 + px) * 4 + 3] = 0;
    }
    // stage raw x tile
    for (int e = tid; e < 5 * 68 * 3; e += 256) {
        int ky = e / 204;
        int rem = e - ky * 204;
        int px = rem / 3, c = rem - px * 3;
        int yg = y + ky - 2, xg = x0 + px - 2;
        float v = 0.f;
        if (yg >= 0 && yg < H_ && (unsigned)xg < W_)
            v = x[(((size_t)((b * T_ + t) * H_ + yg)) * W_ + xg) * 3 + c];
        sxr[(ky * 72 + px) * 4 + c] = f2bf(v);
    }
    // stage h tile (bf16, XOR-swizzled rows)
    if (!first) {
        for (int e = tid; e < 5 * 68 * 8; e += 256) {
            int ky = e / (68 * 8);
            int rem = e - ky * 68 * 8;
            int px = rem >> 3, cg = rem & 7;
            int yg = y + ky - 2, xg = x0 + px - 2;
            uint4 v = make_uint4(0, 0, 0, 0);
            if (yg >= 0 && yg < H_ && (unsigned)xg < W_)
                v = *(const uint4*)(h_prev + ((((size_t)(b * H_ + yg)) * W_ + xg) << 6) + cg * 8);
            int off = ((ky * 68 + px) * 128 + cg * 16) ^ ((px & 7) << 4);
            *(uint4*)(sh + off) = v;
        }
    }
    __syncthreads();

    f32x4 acc[4][4];
#pragma unroll
    for (int rf = 0; rf < 4; ++rf)
#pragma unroll
        for (int g = 0; g < 4; ++g) acc[rf][g] = (f32x4){0.f, 0.f, 0.f, 0.f};

    // x-conv: 5 K-steps, A built from raw tile via scalar LDS gathers
    for (int ky = 0; ky < 5; ++ky) {
        bf16x8 a[4], bb[4];
#pragma unroll
        for (int rf = 0; rf < 4; ++rf) {
            int base = (ky * 72 + rf * 16 + m0) * 4;
            union { bf16x8 v; unsigned short u[8]; } tt;
#pragma unroll
            for (int j = 0; j < 8; ++j) tt.u[j] = sxr[base + dj[j]];
            a[rf] = tt.v;
        }
#pragma unroll
        for (int g = 0; g < 4; ++g)
            bb[g] = *(const bf16x8*)(wxr + ((size_t)((ky * 16 + g * 4 + w) * 64 + l)) * 8);
#pragma unroll
        for (int rf = 0; rf < 4; ++rf)
#pragma unroll
            for (int g = 0; g < 4; ++g)
                acc[rf][g] = __builtin_amdgcn_mfma_f32_16x16x32_bf16(a[rf], bb[g], acc[rf][g], 0, 0, 0);
    }

    // h-conv: 50 K-steps, fully unrolled; LDS addrs = V[kx][ch] + literal offset
    if (!first) {
        int V[5][2];
#pragma unroll
        for (int kx = 0; kx < 5; ++kx) {
            int T = ((m0 + kx) & 7) << 4;
#pragma unroll
            for (int ch = 0; ch < 2; ++ch)
                V[kx][ch] = ((m0 + kx) * 128 + ch * 64 + kq * 16) ^ T;
        }
        const char* shb = sh;
        const char* wb = (const char*)whr + (size_t)w * 1024 + (size_t)l * 16;
#pragma unroll
        for (int ky = 0; ky < 5; ++ky)
#pragma unroll
        for (int kx = 0; kx < 5; ++kx)
#pragma unroll
        for (int ch = 0; ch < 2; ++ch) {
            const int s = (ky * 5 + kx) * 2 + ch;
            bf16x8 a[4], bb[4];
#pragma unroll
            for (int g = 0; g < 4; ++g)
                bb[g] = *(const bf16x8*)(wb + (size_t)s * 16384 + g * 4096);
#pragma unroll
            for (int rf = 0; rf < 4; ++rf)
                a[rf] = *(const bf16x8*)(shb + (V[kx][ch] + (ky * 8704 + rf * 2048)));
#pragma unroll
            for (int rf = 0; rf < 4; ++rf)
#pragma unroll
                for (int g = 0; g < 4; ++g)
                    acc[rf][g] = __builtin_amdgcn_mfma_f32_16x16x32_bf16(a[rf], bb[g], acc[rf][g], 0, 0, 0);
        }
    }

    const int f = (w << 4) + m0;
    const float bi0 = bias[f], bi1 = bias[64 + f], bi2 = bias[128 + f], bi3 = bias[192 + f];
    // fused BN constants (used only when last)
    float bn_s = 0.f, bn_b = 0.f, bn_m = 0.f;
    if (last) {
        bn_s = rsqrtf(mvar[f] + 1e-3f) * gamma[f];
        bn_b = beta[f];
        bn_m = mmean[f];
    }
#pragma unroll
    for (int rf = 0; rf < 4; ++rf) {
#pragma unroll
        for (int r = 0; r < 4; ++r) {
            int px = x0 + rf * 16 + kq * 4 + r;
            size_t idx = ((((size_t)(b * H_ + y)) * W_ + px) << 6) + f;
            float zi = acc[rf][0][r] + bi0;
            float zf = acc[rf][1][r] + bi1;
            float zc = acc[rf][2][r] + bi2;
            float zo = acc[rf][3][r] + bi3;
            float cp = first ? 0.f : c_io[idx];
            float cn = hs_(zf) * cp + hs_(zi) * tanhf(zc);
            float hn = hs_(zo) * tanhf(cn);
            if (last) {
                h_out[idx] = f2bf((hn - bn_m) * bn_s + bn_b);
            } else {
                c_io[idx] = cn;
                h_out[idx] = f2bf(hn);
            }
        }
    }
}

// ---- generic MFMA conv: bf16 in [B,H,W,CIN] -> ReLU -> bf16 out [B,H,W,COUT] ----
template <int KH, int KW, int CIN, int COUT, int KYB>
__global__ __launch_bounds__(256) void conv_mfma(
    const unsigned short* __restrict__ in, const unsigned short* __restrict__ wr,
    const float* __restrict__ bias, unsigned short* __restrict__ out)
{
    constexpr int TC = 64 + KW - 1;
    constexpr int PADX = KW / 2, PADY = KH / 2;
    constexpr int NF = COUT / 16;
    constexpr int CHN = (CIN + 31) / 32;
    constexpr int NKG = KH / KYB;
    __shared__ char sh[KYB * TC * 128];

    const int b = blockIdx.z, y = blockIdx.y, x0 = blockIdx.x * 64;
    const int tid = threadIdx.x;
    const int w = tid >> 6, l = tid & 63;
    const int m0 = l & 15, kq = l >> 4;

    f32x4 acc[NF];
#pragma unroll
    for (int nf = 0; nf < NF; ++nf) acc[nf] = (f32x4){0.f, 0.f, 0.f, 0.f};

    for (int kg = 0; kg < NKG; ++kg) {
        __syncthreads();
        for (int e = tid; e < KYB * TC * 8; e += 256) {
            int kyl = e / (TC * 8);
            int rem = e - kyl * TC * 8;
            int px = rem >> 3, cg = rem & 7;
            int ky = kg * KYB + kyl;
            int yg = y + ky - PADY, xg = x0 + px - PADX;
            int c0 = cg * 8;
            uint4 v = make_uint4(0, 0, 0, 0);
            if (yg >= 0 && yg < H_ && (unsigned)xg < W_ && c0 < CIN)
                v = *(const uint4*)(in + ((size_t)((b * H_ + yg) * W_) + xg) * CIN + c0);
            int off = ((kyl * TC + px) * 128 + cg * 16) ^ ((px & 7) << 4);
            *(uint4*)(sh + off) = v;
        }
        __syncthreads();

        for (int kyl = 0; kyl < KYB; ++kyl) {
            int ky = kg * KYB + kyl;
#pragma unroll
            for (int kx = 0; kx < KW; ++kx) {
#pragma unroll
                for (int ch = 0; ch < CHN; ++ch) {
                    int px = w * 16 + m0 + kx;
                    int off = ((kyl * TC + px) * 128 + ch * 64 + kq * 16) ^ ((px & 7) << 4);
                    bf16x8 a = *(const bf16x8*)(sh + off);
                    int tap = ky * KW + kx;
                    const unsigned short* wp = wr + ((size_t)(((tap * 2 + ch) * NF) * 64 + l)) * 8;
#pragma unroll
                    for (int nf = 0; nf < NF; ++nf) {
                        bf16x8 bb = *(const bf16x8*)(wp + nf * 512);
                        acc[nf] = __builtin_amdgcn_mfma_f32_16x16x32_bf16(a, bb, acc[nf], 0, 0, 0);
                    }
                }
            }
        }
    }

#pragma unroll
    for (int nf = 0; nf < NF; ++nf) {
        int cout = nf * 16 + m0;
        float bv = bias[cout];
#pragma unroll
        for (int r = 0; r < 4; ++r) {
            int px = x0 + w * 16 + kq * 4 + r;
            float v = fmaxf(acc[nf][r] + bv, 0.f);
            out[((size_t)((b * H_ + y) * W_) + px) * COUT + cout] = f2bf(v);
        }
    }
}

// -------- conv5: 3x3, 64 -> 3, sigmoid; bf16 in, f32 out --------
__global__ __launch_bounds__(256) void conv5_k(
    const unsigned short* __restrict__ in, const float* __restrict__ wgt,
    const float* __restrict__ bias, float* __restrict__ out)
{
    constexpr int CC = 16;
    __shared__ float s[3][W_ + 2][CC + 1];
    const int b = blockIdx.z, y = blockIdx.y;
    const int tid = threadIdx.x;

    float acc[3] = {0.f, 0.f, 0.f};
    for (int c0 = 0; c0 < 64; c0 += CC) {
        __syncthreads();
        for (int e = tid; e < 3 * (W_ + 2) * CC; e += 256) {
            int r = e / ((W_ + 2) * CC);
            int rem = e % ((W_ + 2) * CC);
            int cc = rem / CC, ch = rem % CC;
            int yg = y + r - 1, xg = cc - 1;
            float v = 0.f;
            if (yg >= 0 && yg < H_ && xg >= 0 && xg < W_)
                v = bf2f(in[((b * H_ + yg) * W_ + xg) * 64 + c0 + ch]);
            s[r][cc][ch] = v;
        }
        __syncthreads();
        for (int ky = 0; ky < 3; ++ky) {
#pragma unroll
            for (int kx = 0; kx < 3; ++kx) {
                for (int c = 0; c < CC; ++c) {
                    const float* wp = &wgt[((ky * 3 + kx) * 64 + c0 + c) * 3];
                    float v = s[ky][tid + kx][c];
                    acc[0] = fmaf(v, wp[0], acc[0]);
                    acc[1] = fmaf(v, wp[1], acc[1]);
                    acc[2] = fmaf(v, wp[2], acc[2]);
                }
            }
        }
    }
#pragma unroll
    for (int j = 0; j < 3; ++j) {
        float v = acc[j] + bias[j];
        v = 1.f / (1.f + expf(-v));
        out[((b * H_ + y) * W_ + tid) * 3 + j] = v;
    }
}

extern "C" void kernel_launch(void* const* d_in, const int* in_sizes, int n_in,
                              void* d_out, int out_size, void* d_ws, size_t ws_size,
                              hipStream_t stream) {
    const float* x     = (const float*)d_in[0];
    const float* Wx    = (const float*)d_in[1];
    const float* Wh    = (const float*)d_in[2];
    const float* bl    = (const float*)d_in[3];
    const float* gamma = (const float*)d_in[4];
    const float* beta  = (const float*)d_in[5];
    const float* mmean = (const float*)d_in[6];
    const float* mvar  = (const float*)d_in[7];
    const float* W1 = (const float*)d_in[8];
    const float* b1 = (const float*)d_in[9];
    const float* W2 = (const float*)d_in[10];
    const float* b2 = (const float*)d_in[11];
    const float* W3 = (const float*)d_in[12];
    const float* b3 = (const float*)d_in[13];
    const float* W4 = (const float*)d_in[14];
    const float* b4 = (const float*)d_in[15];
    const float* W5 = (const float*)d_in[16];
    const float* b5 = (const float*)d_in[17];
    float* out = (float*)d_out;

    const size_t NHWF = (size_t)B_ * H_ * W_ * 64;  // 9.44M
    char* p = (char*)d_ws;
    float* c_buf = (float*)p;                 p += NHWF * 4;
    unsigned short* hA = (unsigned short*)p;  p += NHWF * 2;
    unsigned short* hB = (unsigned short*)p;  p += NHWF * 2;
    unsigned short* whr = (unsigned short*)p; p += (size_t)25 * 2 * 16 * 64 * 8 * 2;
    unsigned short* wxr = (unsigned short*)p; p += (size_t)5 * 16 * 64 * 8 * 2;
    unsigned short* w1r = (unsigned short*)p; p += (size_t)81 * 2 * 1 * 512 * 2;
    unsigned short* w2r = (unsigned short*)p; p += (size_t)25 * 2 * 2 * 512 * 2;
    unsigned short* w3r = (unsigned short*)p; p += (size_t)9 * 2 * 4 * 512 * 2;
    unsigned short* w4r = (unsigned short*)p; p += (size_t)9 * 2 * 4 * 512 * 2;

    repack_wh_mfma<<<(25 * 2 * 4 * 4 * 64 + 255) / 256, 256, 0, stream>>>(Wh, whr);
    repack_wx_mfma<<<(5 * 4 * 4 * 64 + 255) / 256, 256, 0, stream>>>(Wx, wxr);
    repack_conv<<<(81 * 2 * 1 * 64 + 255) / 256, 256, 0, stream>>>(W1, w1r, 81, 64, 16);
    repack_conv<<<(25 * 2 * 2 * 64 + 255) / 256, 256, 0, stream>>>(W2, w2r, 25, 16, 32);
    repack_conv<<<(9 * 2 * 4 * 64 + 255) / 256, 256, 0, stream>>>(W3, w3r, 9, 32, 64);
    repack_conv<<<(9 * 2 * 4 * 64 + 255) / 256, 256, 0, stream>>>(W4, w4r, 9, 64, 64);

    dim3 lgrid(W_ / MT, H_, B_);
    for (int t = 0; t < T_; ++t) {
        const unsigned short* hp = (t & 1) ? hA : hB;
        unsigned short* ho = (t & 1) ? hB : hA;
        lstm_mfma<<<lgrid, 256, 0, stream>>>(x, wxr, whr, bl, hp, ho, c_buf,
                                             gamma, beta, mmean, mvar,
                                             t, t == 0 ? 1 : 0, t == T_ - 1 ? 1 : 0);
    }
    // t=9 wrote BN'd final h into hB (bf16)

    unsigned short* o1 = (unsigned short*)c_buf;
    unsigned short* o2 = o1 + NHWF / 4;
    unsigned short* o3 = hA;
    unsigned short* o4 = hB;

    dim3 cgrid(W_ / 64, H_, B_);
    conv_mfma<9, 9, 64, 16, 3><<<cgrid, 256, 0, stream>>>(hB, w1r, b1, o1);
    conv_mfma<5, 5, 16, 32, 5><<<cgrid, 256, 0, stream>>>(o1, w2r, b2, o2);
    conv_mfma<3, 3, 32, 64, 3><<<cgrid, 256, 0, stream>>>(o2, w3r, b3, o3);
    conv_mfma<3, 3, 64, 64, 3><<<cgrid, 256, 0, stream>>>(o3, w4r, b4, o4);
    conv5_k<<<dim3(1, H_, B_), 256, 0, stream>>>(o4, W5, b5, out);
}

// Round 14
// 1448.046 us; speedup vs baseline: 1.1271x; 1.0403x over previous
//
#include <hip/hip_runtime.h>
#include <math.h>

#define B_ 4
#define T_ 10
#define H_ 144
#define W_ 256
#define F_ 64

typedef __attribute__((ext_vector_type(8))) __bf16 bf16x8;
typedef __attribute__((ext_vector_type(4))) float f32x4;

static __device__ __forceinline__ float hs_(float x) {
    return fminf(fmaxf(fmaf(x, 0.2f, 0.5f), 0.f), 1.f);
}
static __device__ __forceinline__ unsigned short f2bf(float f) {
    unsigned u = __builtin_bit_cast(unsigned, f);
    u += 0x7fff + ((u >> 16) & 1);
    return (unsigned short)(u >> 16);
}
static __device__ __forceinline__ float bf2f(unsigned short s) {
    unsigned u = ((unsigned)s) << 16;
    return __builtin_bit_cast(float, u);
}

// ---- repack Wh [5][5][64][256] -> [25][2][4 gate][4 wf][64 lane][8] bf16 ----
__global__ void repack_wh_mfma(const float* __restrict__ w, unsigned short* __restrict__ o) {
    int idx = blockIdx.x * 256 + threadIdx.x;
    if (idx >= 25 * 2 * 4 * 4 * 64) return;
    int l = idx & 63;
    int wf = (idx >> 6) & 3;
    int g = (idx >> 8) & 3;
    int ch = (idx >> 10) & 1;
    int tap = idx >> 11;
    int n = g * 64 + wf * 16 + (l & 15);
    unsigned short* dst = o + (size_t)idx * 8;
#pragma unroll
    for (int j = 0; j < 8; ++j) {
        int c = ch * 32 + (l >> 4) * 8 + j;
        dst[j] = f2bf(w[((size_t)(tap * 64 + c)) * 256 + n]);
    }
}

// ---- repack Wx [5][5][3][256] -> [5 ky][4 gate][4 wf][64 lane][8] bf16 ----
__global__ void repack_wx_mfma(const float* __restrict__ w, unsigned short* __restrict__ o) {
    int idx = blockIdx.x * 256 + threadIdx.x;
    if (idx >= 5 * 4 * 4 * 64) return;
    int l = idx & 63;
    int wf = (idx >> 6) & 3;
    int g = (idx >> 8) & 3;
    int ky = idx >> 10;
    int n = g * 64 + wf * 16 + (l & 15);
    unsigned short* dst = o + (size_t)idx * 8;
#pragma unroll
    for (int j = 0; j < 8; ++j) {
        int k = (l >> 4) * 8 + j;
        unsigned short v = 0;
        if (k < 15) {
            int kx = k / 3, c = k - kx * 3;
            v = f2bf(w[((size_t)((ky * 5 + kx) * 3 + c)) * 256 + n]);
        }
        dst[j] = v;
    }
}

// ---- generic conv weight repack: [taps][CIN][COUT] f32 -> [tap][2ch][NF][64][8] bf16 ----
__global__ void repack_conv(const float* __restrict__ w, unsigned short* __restrict__ o,
                            int taps, int cin, int cout) {
    int NF = cout >> 4;
    int total = taps * 2 * NF * 64;
    int idx = blockIdx.x * 256 + threadIdx.x;
    if (idx >= total) return;
    int l = idx & 63;
    int nf = (idx >> 6) % NF;
    int ch = ((idx >> 6) / NF) & 1;
    int tap = (idx >> 6) / NF / 2;
    int n = nf * 16 + (l & 15);
    unsigned short* dst = o + (size_t)idx * 8;
#pragma unroll
    for (int j = 0; j < 8; ++j) {
        int c = ch * 32 + (l >> 4) * 8 + j;
        dst[j] = (c < cin) ? f2bf(w[((size_t)(tap * cin + c)) * cout + n]) : (unsigned short)0;
    }
}

// ---- fused ConvLSTM step via bf16 MFMA (r11 structure + lean staging + setprio) ----
// block = 4 waves; wave w: 64 px x f [16w,16w+16) x all 4 gates
// LDS h-tile row ky: byte = ((ky*68+px)*128 + cg*16) ^ ((px&7)<<4)
// A addr = V[kx][ch] + ky*8704 + rf*2048
#define MT 64
__global__ __launch_bounds__(256, 3) void lstm_mfma(
    const float* __restrict__ x,
    const unsigned short* __restrict__ wxr,
    const unsigned short* __restrict__ whr,
    const float* __restrict__ bias,
    const unsigned short* __restrict__ h_prev,
    unsigned short* __restrict__ h_out,
    float* __restrict__ c_io,
    int t, int first)
{
    __shared__ char sh[5 * 68 * 128];           // swizzled bf16 h tile = 43520 B
    __shared__ unsigned short sxr[5 * 72 * 4];  // raw bf16 x tile = 2880 B

    const int b = blockIdx.z, y = blockIdx.y, x0 = blockIdx.x * MT;
    const int tid = threadIdx.x;
    const int w = tid >> 6, l = tid & 63;
    const int m0 = l & 15, kq = l >> 4;

    // per-thread k -> (kx*4+c) table for x A-frag gathers (invalid -> c=3 zero slot)
    int dj[8];
#pragma unroll
    for (int j = 0; j < 8; ++j) {
        int k = kq * 8 + j;
        int kx = k / 3, c = k - kx * 3;
        dj[j] = (k < 15) ? kx * 4 + c : 3;
    }

    // ---- x staging: structured, zero-column folded (cx==3 writes 0) ----
    {
        const int cx = tid & 3, pxr = tid >> 2;   // pxr in [0,64)
        const bool xv0 = (cx < 3) && ((unsigned)(x0 + pxr - 2) < W_);
        const bool xv1 = (cx < 3) && (pxr < 4) && ((unsigned)(x0 + pxr + 62) < W_);
        const float* xb = x + ((size_t)((b * T_ + t) * H_)) * W_ * 3;
#pragma unroll
        for (int ky = 0; ky < 5; ++ky) {
            const int yg = y + ky - 2;
            float v0 = 0.f, v1 = 0.f;
            if (yg >= 0 && yg < H_) {             // wave-uniform branch
                const float* rp = xb + ((size_t)yg * W_ + (x0 + pxr - 2)) * 3 + cx;
                if (xv0) v0 = rp[0];
                if (xv1) v1 = rp[64 * 3];
            }
            sxr[(ky * 72 + pxr) * 4 + cx] = f2bf(v0);
            if (pxr < 4) sxr[(ky * 72 + pxr + 64) * 4 + cx] = f2bf(v1);
        }
    }
    // ---- h staging: structured, literal LDS offsets, uniform row bounds ----
    if (!first) {
        const int tr = tid >> 3;                  // px-lane, [0,32)
        const int cg = tid & 7;                   // 16B granule
        const int xorv = (tr & 7) << 4;           // (px&7)<<4 invariant for px=tr+32i
        char* lp = sh + tr * 128 + ((cg * 16) ^ xorv);
        const bool mk0 = (unsigned)(x0 + tr - 2) < W_;
        const bool mk2 = (tr < 4) && ((unsigned)(x0 + tr + 62) < W_);
        const uint4 zz = make_uint4(0, 0, 0, 0);
#pragma unroll
        for (int ky = 0; ky < 5; ++ky) {
            const int yg = y + ky - 2;
            uint4 v0 = zz, v1 = zz, v2 = zz;
            if (yg >= 0 && yg < H_) {             // wave-uniform branch
                const unsigned short* rp = h_prev
                    + (((size_t)(b * H_ + yg)) * W_ + (x0 + tr - 2)) * 64 + cg * 8;
                if (mk0) v0 = *(const uint4*)rp;
                v1 = *(const uint4*)(rp + 2048);  // px+32 always in-bounds
                if (mk2) v2 = *(const uint4*)(rp + 4096);
            }
            *(uint4*)(lp + ky * 8704)        = v0;
            *(uint4*)(lp + ky * 8704 + 4096) = v1;
            if (tr < 4) *(uint4*)(lp + ky * 8704 + 8192) = v2;
        }
    }
    __syncthreads();

    f32x4 acc[4][4];
#pragma unroll
    for (int rf = 0; rf < 4; ++rf)
#pragma unroll
        for (int g = 0; g < 4; ++g) acc[rf][g] = (f32x4){0.f, 0.f, 0.f, 0.f};

    // x-conv: 5 K-steps, A built from raw tile via scalar LDS gathers
    for (int ky = 0; ky < 5; ++ky) {
        bf16x8 a[4], bb[4];
#pragma unroll
        for (int rf = 0; rf < 4; ++rf) {
            int base = (ky * 72 + rf * 16 + m0) * 4;
            union { bf16x8 v; unsigned short u[8]; } tt;
#pragma unroll
            for (int j = 0; j < 8; ++j) tt.u[j] = sxr[base + dj[j]];
            a[rf] = tt.v;
        }
#pragma unroll
        for (int g = 0; g < 4; ++g)
            bb[g] = *(const bf16x8*)(wxr + ((size_t)((ky * 16 + g * 4 + w) * 64 + l)) * 8);
        __builtin_amdgcn_s_setprio(1);
#pragma unroll
        for (int rf = 0; rf < 4; ++rf)
#pragma unroll
            for (int g = 0; g < 4; ++g)
                acc[rf][g] = __builtin_amdgcn_mfma_f32_16x16x32_bf16(a[rf], bb[g], acc[rf][g], 0, 0, 0);
        __builtin_amdgcn_s_setprio(0);
    }

    // h-conv: 50 K-steps; ky rotated per block (r11); setprio around MFMA cluster
    if (!first) {
        int V[5][2];
#pragma unroll
        for (int kx = 0; kx < 5; ++kx) {
            int T = ((m0 + kx) & 7) << 4;
#pragma unroll
            for (int ch = 0; ch < 2; ++ch)
                V[kx][ch] = ((m0 + kx) * 128 + ch * 64 + kq * 16) ^ T;
        }
        const char* shb = sh;
        const char* wb = (const char*)whr + (size_t)w * 1024 + (size_t)l * 16;
        const int koff = (blockIdx.x * 7 + blockIdx.y * 3 + blockIdx.z) % 5;

        for (int kyi = 0; kyi < 5; ++kyi) {
            int ky = kyi + koff;
            if (ky >= 5) ky -= 5;                   // scalar
            const int kyA = ky * 8704;              // scalar
            const char* wbk = wb + (size_t)ky * 10 * 16384;
#pragma unroll
            for (int kx = 0; kx < 5; ++kx)
#pragma unroll
            for (int ch = 0; ch < 2; ++ch) {
                const int s = kx * 2 + ch;          // compile-time within ky group
                bf16x8 a[4], bb[4];
#pragma unroll
                for (int g = 0; g < 4; ++g)
                    bb[g] = *(const bf16x8*)(wbk + (size_t)s * 16384 + g * 4096);
#pragma unroll
                for (int rf = 0; rf < 4; ++rf)
                    a[rf] = *(const bf16x8*)(shb + (V[kx][ch] + kyA + rf * 2048));
                __builtin_amdgcn_s_setprio(1);
#pragma unroll
                for (int rf = 0; rf < 4; ++rf)
#pragma unroll
                    for (int g = 0; g < 4; ++g)
                        acc[rf][g] = __builtin_amdgcn_mfma_f32_16x16x32_bf16(a[rf], bb[g], acc[rf][g], 0, 0, 0);
                __builtin_amdgcn_s_setprio(0);
            }
        }
    }

    const int f = (w << 4) + m0;
    const float bi0 = bias[f], bi1 = bias[64 + f], bi2 = bias[128 + f], bi3 = bias[192 + f];
#pragma unroll
    for (int rf = 0; rf < 4; ++rf) {
#pragma unroll
        for (int r = 0; r < 4; ++r) {
            int px = x0 + rf * 16 + kq * 4 + r;
            size_t idx = ((((size_t)(b * H_ + y)) * W_ + px) << 6) + f;
            float zi = acc[rf][0][r] + bi0;
            float zf = acc[rf][1][r] + bi1;
            float zc = acc[rf][2][r] + bi2;
            float zo = acc[rf][3][r] + bi3;
            float cp = first ? 0.f : c_io[idx];
            float cn = hs_(zf) * cp + hs_(zi) * tanhf(zc);
            float hn = hs_(zo) * tanhf(cn);
            c_io[idx] = cn;
            h_out[idx] = f2bf(hn);
        }
    }
}

// -------- BatchNorm (inference), bf16 in -> bf16 out --------
__global__ void bn_k(const unsigned short* __restrict__ in, unsigned short* __restrict__ out,
                     const float* __restrict__ gamma, const float* __restrict__ beta,
                     const float* __restrict__ mean, const float* __restrict__ var, int n) {
    for (int i = blockIdx.x * blockDim.x + threadIdx.x; i < n; i += gridDim.x * blockDim.x) {
        int c = i & 63;
        float s = rsqrtf(var[c] + 1e-3f) * gamma[c];
        out[i] = f2bf((bf2f(in[i]) - mean[c]) * s + beta[c]);
    }
}

// ---- generic MFMA conv: bf16 in [B,H,W,CIN] -> ReLU -> bf16 out [B,H,W,COUT] ----
template <int KH, int KW, int CIN, int COUT, int KYB>
__global__ __launch_bounds__(256) void conv_mfma(
    const unsigned short* __restrict__ in, const unsigned short* __restrict__ wr,
    const float* __restrict__ bias, unsigned short* __restrict__ out)
{
    constexpr int TC = 64 + KW - 1;
    constexpr int PADX = KW / 2, PADY = KH / 2;
    constexpr int NF = COUT / 16;
    constexpr int CHN = (CIN + 31) / 32;
    constexpr int NKG = KH / KYB;
    __shared__ char sh[KYB * TC * 128];

    const int b = blockIdx.z, y = blockIdx.y, x0 = blockIdx.x * 64;
    const int tid = threadIdx.x;
    const int w = tid >> 6, l = tid & 63;
    const int m0 = l & 15, kq = l >> 4;

    f32x4 acc[NF];
#pragma unroll
    for (int nf = 0; nf < NF; ++nf) acc[nf] = (f32x4){0.f, 0.f, 0.f, 0.f};

    for (int kg = 0; kg < NKG; ++kg) {
        __syncthreads();
        for (int e = tid; e < KYB * TC * 8; e += 256) {
            int kyl = e / (TC * 8);
            int rem = e - kyl * TC * 8;
            int px = rem >> 3, cg = rem & 7;
            int ky = kg * KYB + kyl;
            int yg = y + ky - PADY, xg = x0 + px - PADX;
            int c0 = cg * 8;
            uint4 v = make_uint4(0, 0, 0, 0);
            if (yg >= 0 && yg < H_ && (unsigned)xg < W_ && c0 < CIN)
                v = *(const uint4*)(in + ((size_t)((b * H_ + yg) * W_) + xg) * CIN + c0);
            int off = ((kyl * TC + px) * 128 + cg * 16) ^ ((px & 7) << 4);
            *(uint4*)(sh + off) = v;
        }
        __syncthreads();

        for (int kyl = 0; kyl < KYB; ++kyl) {
            int ky = kg * KYB + kyl;
#pragma unroll
            for (int kx = 0; kx < KW; ++kx) {
#pragma unroll
                for (int ch = 0; ch < CHN; ++ch) {
                    int px = w * 16 + m0 + kx;
                    int off = ((kyl * TC + px) * 128 + ch * 64 + kq * 16) ^ ((px & 7) << 4);
                    bf16x8 a = *(const bf16x8*)(sh + off);
                    int tap = ky * KW + kx;
                    const unsigned short* wp = wr + ((size_t)(((tap * 2 + ch) * NF) * 64 + l)) * 8;
#pragma unroll
                    for (int nf = 0; nf < NF; ++nf) {
                        bf16x8 bb = *(const bf16x8*)(wp + nf * 512);
                        acc[nf] = __builtin_amdgcn_mfma_f32_16x16x32_bf16(a, bb, acc[nf], 0, 0, 0);
                    }
                }
            }
        }
    }

#pragma unroll
    for (int nf = 0; nf < NF; ++nf) {
        int cout = nf * 16 + m0;
        float bv = bias[cout];
#pragma unroll
        for (int r = 0; r < 4; ++r) {
            int px = x0 + w * 16 + kq * 4 + r;
            float v = fmaxf(acc[nf][r] + bv, 0.f);
            out[((size_t)((b * H_ + y) * W_) + px) * COUT + cout] = f2bf(v);
        }
    }
}

// -------- conv5: 3x3, 64 -> 3, sigmoid; bf16 in, f32 out --------
__global__ __launch_bounds__(256) void conv5_k(
    const unsigned short* __restrict__ in, const float* __restrict__ wgt,
    const float* __restrict__ bias, float* __restrict__ out)
{
    constexpr int CC = 16;
    __shared__ float s[3][W_ + 2][CC + 1];
    const int b = blockIdx.z, y = blockIdx.y;
    const int tid = threadIdx.x;

    float acc[3] = {0.f, 0.f, 0.f};
    for (int c0 = 0; c0 < 64; c0 += CC) {
        __syncthreads();
        for (int e = tid; e < 3 * (W_ + 2) * CC; e += 256) {
            int r = e / ((W_ + 2) * CC);
            int rem = e % ((W_ + 2) * CC);
            int cc = rem / CC, ch = rem % CC;
            int yg = y + r - 1, xg = cc - 1;
            float v = 0.f;
            if (yg >= 0 && yg < H_ && xg >= 0 && xg < W_)
                v = bf2f(in[((b * H_ + yg) * W_ + xg) * 64 + c0 + ch]);
            s[r][cc][ch] = v;
        }
        __syncthreads();
        for (int ky = 0; ky < 3; ++ky) {
#pragma unroll
            for (int kx = 0; kx < 3; ++kx) {
                for (int c = 0; c < CC; ++c) {
                    const float* wp = &wgt[((ky * 3 + kx) * 64 + c0 + c) * 3];
                    float v = s[ky][tid + kx][c];
                    acc[0] = fmaf(v, wp[0], acc[0]);
                    acc[1] = fmaf(v, wp[1], acc[1]);
                    acc[2] = fmaf(v, wp[2], acc[2]);
                }
            }
        }
    }
#pragma unroll
    for (int j = 0; j < 3; ++j) {
        float v = acc[j] + bias[j];
        v = 1.f / (1.f + expf(-v));
        out[((b * H_ + y) * W_ + tid) * 3 + j] = v;
    }
}

extern "C" void kernel_launch(void* const* d_in, const int* in_sizes, int n_in,
                              void* d_out, int out_size, void* d_ws, size_t ws_size,
                              hipStream_t stream) {
    const float* x     = (const float*)d_in[0];
    const float* Wx    = (const float*)d_in[1];
    const float* Wh    = (const float*)d_in[2];
    const float* bl    = (const float*)d_in[3];
    const float* gamma = (const float*)d_in[4];
    const float* beta  = (const float*)d_in[5];
    const float* mmean = (const float*)d_in[6];
    const float* mvar  = (const float*)d_in[7];
    const float* W1 = (const float*)d_in[8];
    const float* b1 = (const float*)d_in[9];
    const float* W2 = (const float*)d_in[10];
    const float* b2 = (const float*)d_in[11];
    const float* W3 = (const float*)d_in[12];
    const float* b3 = (const float*)d_in[13];
    const float* W4 = (const float*)d_in[14];
    const float* b4 = (const float*)d_in[15];
    const float* W5 = (const float*)d_in[16];
    const float* b5 = (const float*)d_in[17];
    float* out = (float*)d_out;

    const size_t NHWF = (size_t)B_ * H_ * W_ * 64;  // 9.44M
    char* p = (char*)d_ws;
    float* c_buf = (float*)p;                 p += NHWF * 4;
    unsigned short* hA = (unsigned short*)p;  p += NHWF * 2;
    unsigned short* hB = (unsigned short*)p;  p += NHWF * 2;
    unsigned short* whr = (unsigned short*)p; p += (size_t)25 * 2 * 16 * 64 * 8 * 2;
    unsigned short* wxr = (unsigned short*)p; p += (size_t)5 * 16 * 64 * 8 * 2;
    unsigned short* w1r = (unsigned short*)p; p += (size_t)81 * 2 * 1 * 512 * 2;
    unsigned short* w2r = (unsigned short*)p; p += (size_t)25 * 2 * 2 * 512 * 2;
    unsigned short* w3r = (unsigned short*)p; p += (size_t)9 * 2 * 4 * 512 * 2;
    unsigned short* w4r = (unsigned short*)p; p += (size_t)9 * 2 * 4 * 512 * 2;

    repack_wh_mfma<<<(25 * 2 * 4 * 4 * 64 + 255) / 256, 256, 0, stream>>>(Wh, whr);
    repack_wx_mfma<<<(5 * 4 * 4 * 64 + 255) / 256, 256, 0, stream>>>(Wx, wxr);
    repack_conv<<<(81 * 2 * 1 * 64 + 255) / 256, 256, 0, stream>>>(W1, w1r, 81, 64, 16);
    repack_conv<<<(25 * 2 * 2 * 64 + 255) / 256, 256, 0, stream>>>(W2, w2r, 25, 16, 32);
    repack_conv<<<(9 * 2 * 4 * 64 + 255) / 256, 256, 0, stream>>>(W3, w3r, 9, 32, 64);
    repack_conv<<<(9 * 2 * 4 * 64 + 255) / 256, 256, 0, stream>>>(W4, w4r, 9, 64, 64);

    dim3 lgrid(W_ / MT, H_, B_);
    for (int t = 0; t < T_; ++t) {
        const unsigned short* hp = (t & 1) ? hA : hB;
        unsigned short* ho = (t & 1) ? hB : hA;
        lstm_mfma<<<lgrid, 256, 0, stream>>>(x, wxr, whr, bl, hp, ho, c_buf, t, t == 0 ? 1 : 0);
    }
    // final h in hB

    unsigned short* bnb = hA;
    bn_k<<<2048, 256, 0, stream>>>(hB, bnb, gamma, beta, mmean, mvar, (int)NHWF);

    unsigned short* o1 = (unsigned short*)c_buf;
    unsigned short* o2 = o1 + NHWF / 4;
    unsigned short* o3 = hB;
    unsigned short* o4 = hA;

    dim3 cgrid(W_ / 64, H_, B_);
    conv_mfma<9, 9, 64, 16, 3><<<cgrid, 256, 0, stream>>>(bnb, w1r, b1, o1);
    conv_mfma<5, 5, 16, 32, 5><<<cgrid, 256, 0, stream>>>(o1, w2r, b2, o2);
    conv_mfma<3, 3, 32, 64, 3><<<cgrid, 256, 0, stream>>>(o2, w3r, b3, o3);
    conv_mfma<3, 3, 64, 64, 3><<<cgrid, 256, 0, stream>>>(o3, w4r, b4, o4);
    conv5_k<<<dim3(1, H_, B_), 256, 0, stream>>>(o4, W5, b5, out);
}